// Round 1
// baseline (273.404 us; speedup 1.0000x reference)
//
#include <hip/hip_runtime.h>
#include <hip/hip_bf16.h>

#define N 2048
#define B 16
#define LOG2E 1.44269504088896340736f

typedef float v4f __attribute__((ext_vector_type(4)));

// Kernel 1: asum2[b,i] = LOG2E * sum_k |s[b,i] - s[b,k]|
__global__ __launch_bounds__(256) void asum_kernel(const float* __restrict__ s,
                                                   float* __restrict__ asum2) {
    const int b = blockIdx.y;
    const int chunk = blockIdx.x;

    __shared__ float row[N];
    __shared__ float partial[256];
    const v4f* g4 = (const v4f*)(s + b * N);
    v4f* r4 = (v4f*)row;
    r4[threadIdx.x] = g4[threadIdx.x];
    r4[threadIdx.x + 256] = g4[threadIdx.x + 256];
    __syncthreads();

    const int il = threadIdx.x & 127;
    const int half = threadIdx.x >> 7;   // wave-uniform
    const int i = chunk * 128 + il;
    const float si = row[i];
    const v4f* row4 = (const v4f*)(row + half * (N / 2));
    float acc = 0.0f;
#pragma unroll 4
    for (int k = 0; k < N / 8; ++k) {
        v4f rv = row4[k];
        acc += fabsf(si - rv.x) + fabsf(si - rv.y) +
               fabsf(si - rv.z) + fabsf(si - rv.w);
    }
    partial[threadIdx.x] = acc;
    __syncthreads();
    if (threadIdx.x < 128)
        asum2[b * N + i] = LOG2E * (partial[threadIdx.x] + partial[threadIdx.x + 128]);
}

// Kernel 2: each block owns 32 output rows. LDS staged ONCE, barrier ONCE,
// then 4 row-group iterations (8 rows each: 4 waves x 2 rows) with NO
// inter-group barrier — group g+1's LDS reads / fma / exp2 overlap group g's
// store drain. Nontemporal stores: 268 MB output > 256 MB L3.
// grid = (N/32, B), block = 256.
__global__ __launch_bounds__(256) void softmax_rows(const float* __restrict__ s,
                                                    const float* __restrict__ asum2,
                                                    float* __restrict__ out) {
    __shared__ float ls[N];   // s * LOG2E
    __shared__ float la[N];   // asum2 (LOG2E already folded)

    const int t = threadIdx.x;
    const int lane = t & 63;
    const int wave = t >> 6;
    const int b = blockIdx.y;

    {
        const v4f* g4 = (const v4f*)(s + (size_t)b * N);
        const v4f* ga4 = (const v4f*)(asum2 + (size_t)b * N);
        v4f* l4 = (v4f*)ls;
        v4f* m4 = (v4f*)la;
        v4f s0 = g4[t], s1 = g4[t + 256];
        v4f a0 = ga4[t], a1 = ga4[t + 256];
        s0 *= LOG2E; s1 *= LOG2E;
        l4[t] = s0; l4[t + 256] = s1;
        m4[t] = a0; m4[t + 256] = a1;
    }
    __syncthreads();   // the ONLY barrier

    const v4f* ls4 = (const v4f*)ls;
    const v4f* la4 = (const v4f*)la;
    const int base = blockIdx.x * 32;

#pragma unroll 1
    for (int g = 0; g < 4; ++g) {
        const int jA = base + g * 8 + wave;
        const int jB = jA + 4;
        const float cA = (float)(N - 1 - 2 * jA);
        const float cB = (float)(N - 1 - 2 * jB);

        float va[32], vb[32];
#pragma unroll
        for (int c = 0; c < 8; ++c) {
            v4f sv = ls4[c * 64 + lane];
            v4f av = la4[c * 64 + lane];
            va[c * 4 + 0] = sv.x * cA - av.x;  vb[c * 4 + 0] = sv.x * cB - av.x;
            va[c * 4 + 1] = sv.y * cA - av.y;  vb[c * 4 + 1] = sv.y * cB - av.y;
            va[c * 4 + 2] = sv.z * cA - av.z;  vb[c * 4 + 2] = sv.z * cB - av.z;
            va[c * 4 + 3] = sv.w * cA - av.w;  vb[c * 4 + 3] = sv.w * cB - av.w;
        }

        // interleaved max reductions (two independent rows fill each
        // other's shuffle-latency bubbles)
        float mA = va[0], mB = vb[0];
#pragma unroll
        for (int i = 1; i < 32; ++i) { mA = fmaxf(mA, va[i]); mB = fmaxf(mB, vb[i]); }
#pragma unroll
        for (int off = 32; off >= 1; off >>= 1) {
            mA = fmaxf(mA, __shfl_xor(mA, off));
            mB = fmaxf(mB, __shfl_xor(mB, off));
        }

        // interleaved exp2 + sum reductions
        float sA = 0.0f, sB = 0.0f;
#pragma unroll
        for (int i = 0; i < 32; ++i) {
            va[i] = __builtin_amdgcn_exp2f(va[i] - mA);  sA += va[i];
            vb[i] = __builtin_amdgcn_exp2f(vb[i] - mB);  sB += vb[i];
        }
#pragma unroll
        for (int off = 32; off >= 1; off >>= 1) {
            sA += __shfl_xor(sA, off);
            sB += __shfl_xor(sB, off);
        }

        const float rA = 1.0f / sA;
        const float rB = 1.0f / sB;

        v4f* oA = (v4f*)(out + ((size_t)b * N + jA) * N);
        v4f* oB = (v4f*)(out + ((size_t)b * N + jB) * N);
#pragma unroll
        for (int c = 0; c < 8; ++c) {
            v4f o;
            o.x = va[c * 4 + 0] * rA; o.y = va[c * 4 + 1] * rA;
            o.z = va[c * 4 + 2] * rA; o.w = va[c * 4 + 3] * rA;
            __builtin_nontemporal_store(o, &oA[c * 64 + lane]);
            v4f p;
            p.x = vb[c * 4 + 0] * rB; p.y = vb[c * 4 + 1] * rB;
            p.z = vb[c * 4 + 2] * rB; p.w = vb[c * 4 + 3] * rB;
            __builtin_nontemporal_store(p, &oB[c * 64 + lane]);
        }
    }
}

extern "C" void kernel_launch(void* const* d_in, const int* in_sizes, int n_in,
                              void* d_out, int out_size, void* d_ws, size_t ws_size,
                              hipStream_t stream) {
    const float* scores = (const float*)d_in[0];
    float* out = (float*)d_out;
    float* asum2 = (float*)d_ws;   // B*N*4 = 128 KB

    dim3 g1(N / 128, B);
    asum_kernel<<<g1, 256, 0, stream>>>(scores, asum2);

    dim3 g2(N / 32, B);
    softmax_rows<<<g2, 256, 0, stream>>>(scores, asum2, out);
}